// Round 1
// baseline (325.915 us; speedup 1.0000x reference)
//
#include <hip/hip_runtime.h>
#include <hip/hip_fp16.h>
#include <math.h>

// GlGraphConv: out = x@W0 + A@(x@W1) + 0.5 * f@maxpool2(x@W2) + bias
// A-mix folded into input side: xmix[b,i] = al[i]*x[b,i-1] + ar[i]*x[b,i+1]
// so out_gemm = x@W0 + xmix@W1 (single accumulator), h3 pooled via LDS.

typedef _Float16 f16;
typedef _Float16 f16x4 __attribute__((ext_vector_type(4)));
typedef _Float16 f16x8 __attribute__((ext_vector_type(8)));
typedef float f32x4 __attribute__((ext_vector_type(4)));

// ---- workspace layout (bytes) ----
// Wt : f16[3][256][256]  (m, g, k) k-contiguous   @ 0      (393216 B)
// al : float[16]                                  @ 393216
// ar : float[16]                                  @ 393280
// f  : float[16][8]                               @ 393344
#define WS_AL 393216
#define WS_AR (393216 + 64)
#define WS_F  (393216 + 128)

#define NEG_BIG (-9e15f)

// ============================ prep kernel ============================
__global__ __launch_bounds__(256) void prep_kernel(
    const float* __restrict__ W, const float* __restrict__ MM,
    const float* __restrict__ e, const int* __restrict__ rows,
    const int* __restrict__ cols, char* __restrict__ ws)
{
  int bid = blockIdx.x;
  if (bid < 192) {
    // transpose W[m][k][g] -> Wt[m][g][k] fp16, 32x32 LDS tiles
    __shared__ float t[32][33];
    int m = bid / 64, tile = bid % 64;
    int gi = (tile / 8) * 32, ki = (tile % 8) * 32;
    int tr = threadIdx.x >> 5, tc = threadIdx.x & 31;
    const float* src = W + m * 65536;
    f16* dst = (f16*)ws + m * 65536;
#pragma unroll
    for (int i = 0; i < 4; i++)
      t[tr + 8 * i][tc] = src[(ki + tr + 8 * i) * 256 + gi + tc];
    __syncthreads();
#pragma unroll
    for (int i = 0; i < 4; i++)
      dst[(gi + tr + 8 * i) * 256 + ki + tc] = (f16)t[tc][tr + 8 * i];
  } else {
    // dense 16x16 scatter + row softmax -> al/ar ; f = softmax(MM, axis=1)
    __shared__ float Arow[16][17];
    int tid = threadIdx.x;
    if (tid < 16) {
      for (int c = 0; c < 16; c++) Arow[tid][c] = NEG_BIG;
    }
    __syncthreads();
    if (tid < 48) Arow[rows[tid]][cols[tid]] = e[tid];
    __syncthreads();
    if (tid < 16) {
      float mx = -INFINITY;
      for (int c = 0; c < 16; c++) mx = fmaxf(mx, Arow[tid][c]);
      float d = 0.f;
      for (int c = 0; c < 16; c++) d += expf(Arow[tid][c] - mx);
      // after softmax, diag is zeroed; only neighbors survive in the mix
      float al = expf(Arow[tid][(tid + 15) & 15] - mx) / d;
      float ar = expf(Arow[tid][(tid + 1) & 15] - mx) / d;
      ((float*)(ws + WS_AL))[tid] = al;
      ((float*)(ws + WS_AR))[tid] = ar;
    }
    if (tid >= 64 && tid < 80) {
      int i = tid - 64;
      float v[8];
      float mx = -INFINITY;
      for (int k = 0; k < 8; k++) { v[k] = MM[i * 8 + k]; mx = fmaxf(mx, v[k]); }
      float d = 0.f;
      for (int k = 0; k < 8; k++) d += expf(v[k] - mx);
      for (int k = 0; k < 8; k++)
        ((float*)(ws + WS_F))[i * 8 + k] = expf(v[k] - mx) / d;
    }
  }
}

// ============================ main kernel ============================
// grid: 4096 = 2048 row-tiles (64 rows = 4 batches) x 2 g-tiles (128)
// block: 256 thr = 4 waves; wave w owns rows 0..63 x g [w*32, w*32+32)
// LDS stage: xs f16[64][40] @0, xmixs @5120, wl f16[3][128][40] @10240  (40960 B)
// LDS epi  : h3l f32[64][132] @0 (33792 B, overlaps stage region)
#define XS_STR 40
#define WL_STR 40

__global__ __launch_bounds__(256, 2) void glgc_main(
    const float* __restrict__ x, const float* __restrict__ bias,
    const char* __restrict__ ws, float* __restrict__ out)
{
  __shared__ __align__(16) char smem[40960];
  f16* xs = (f16*)smem;
  f16* xm = (f16*)(smem + 5120);
  f16* wl = (f16*)(smem + 10240);
  float* h3l = (float*)smem;

  const f16* Wt = (const f16*)ws;
  const float* alf = (const float*)(ws + WS_AL);
  const float* arf = (const float*)(ws + WS_AR);
  const float* fm  = (const float*)(ws + WS_F);

  int bid = blockIdx.x;
  int gt = bid & 1, bt = bid >> 1;
  int row0 = bt * 64;   // global row = b*16 + joint
  int g0 = gt * 128;

  int tid = threadIdx.x;
  int w = tid >> 6, lane = tid & 63;
  int lg = lane >> 4, lc = lane & 15;

  // ---- staging maps ----
  // x/xmix: thread -> row sr = tid>>2, k-quarter sq = tid&3 (k = sq*8..+7)
  int sr = tid >> 2, sq = tid & 3;
  int si = sr & 15;
  int rp = (sr & ~15) | ((si + 15) & 15);
  int rn = (sr & ~15) | ((si + 1) & 15);
  float al_i = alf[si], ar_i = arf[si];
  const float* xg  = x + (row0 + sr) * 256 + sq * 8;
  const float* xgp = x + (row0 + rp) * 256 + sq * 8;
  const float* xgn = x + (row0 + rn) * 256 + sq * 8;
  f16* xs_w = xs + sr * XS_STR + sq * 8;
  f16* xm_w = xm + sr * XS_STR + sq * 8;

  f32x4 accO[4][2] = {};  // x@W0 + xmix@W1
  f32x4 accH[4][2] = {};  // x@W2

  for (int kc = 0; kc < 8; kc++) {
    int k0 = kc * 32;
    __syncthreads();
    // ---- stage x and xmix (fp32 -> fp16, mix coeffs applied in fp32) ----
#pragma unroll
    for (int j = 0; j < 2; j++) {
      float4 v  = *(const float4*)(xg  + k0 + j * 4);
      float4 vp = *(const float4*)(xgp + k0 + j * 4);
      float4 vn = *(const float4*)(xgn + k0 + j * 4);
      f16x4 sv = {(f16)v.x, (f16)v.y, (f16)v.z, (f16)v.w};
      f16x4 mv = {(f16)(al_i * vp.x + ar_i * vn.x),
                  (f16)(al_i * vp.y + ar_i * vn.y),
                  (f16)(al_i * vp.z + ar_i * vn.z),
                  (f16)(al_i * vp.w + ar_i * vn.w)};
      *(f16x4*)(xs_w + j * 4) = sv;
      *(f16x4*)(xm_w + j * 4) = mv;
    }
    // ---- stage W (fp16, already transposed: Wt[m][g][k]) ----
#pragma unroll
    for (int t = 0; t < 6; t++) {
      int idx = tid + t * 256;
      int m = idx >> 9, rem = idx & 511;
      int g = rem >> 2, k8 = rem & 3;
      const f16* src = Wt + (m << 16) + (g0 + g) * 256 + k0 + k8 * 8;
      uint4 v = *(const uint4*)src;
      *(uint4*)(wl + m * 5120 + g * WL_STR + k8 * 8) = v;
    }
    __syncthreads();
    // ---- fragments ----
    f16x8 xa[4], xma[4];
#pragma unroll
    for (int m = 0; m < 4; m++) {
      xa[m]  = *(const f16x8*)(xs + (m * 16 + lc) * XS_STR + lg * 8);
      xma[m] = *(const f16x8*)(xm + (m * 16 + lc) * XS_STR + lg * 8);
    }
    f16x8 wb0[2], wb1[2], wb2[2];
#pragma unroll
    for (int n = 0; n < 2; n++) {
      int gg = w * 32 + n * 16 + lc;
      wb0[n] = *(const f16x8*)(wl + 0 * 5120 + gg * WL_STR + lg * 8);
      wb1[n] = *(const f16x8*)(wl + 1 * 5120 + gg * WL_STR + lg * 8);
      wb2[n] = *(const f16x8*)(wl + 2 * 5120 + gg * WL_STR + lg * 8);
    }
    // ---- MFMA: 24 per chunk per wave ----
#pragma unroll
    for (int m = 0; m < 4; m++) {
#pragma unroll
      for (int n = 0; n < 2; n++) {
        accO[m][n] = __builtin_amdgcn_mfma_f32_16x16x32_f16(xa[m],  wb0[n], accO[m][n], 0, 0, 0);
        accO[m][n] = __builtin_amdgcn_mfma_f32_16x16x32_f16(xma[m], wb1[n], accO[m][n], 0, 0, 0);
        accH[m][n] = __builtin_amdgcn_mfma_f32_16x16x32_f16(xa[m],  wb2[n], accH[m][n], 0, 0, 0);
      }
    }
  }

  // ---- epilogue: pool h3 over joint pairs, mix with f, add bias ----
  __syncthreads();
#pragma unroll
  for (int m = 0; m < 4; m++) {
#pragma unroll
    for (int n = 0; n < 2; n++) {
      int col = w * 32 + n * 16 + lc;
#pragma unroll
      for (int r = 0; r < 4; r++)
        h3l[(m * 16 + lg * 4 + r) * 132 + col] = accH[m][n][r];
    }
  }
  __syncthreads();

  float fc[4][8];
#pragma unroll
  for (int r = 0; r < 4; r++)
#pragma unroll
    for (int k = 0; k < 8; k++)
      fc[r][k] = fm[(lg * 4 + r) * 8 + k];
  float b0 = bias[g0 + w * 32 + lc];
  float b1 = bias[g0 + w * 32 + 16 + lc];

#pragma unroll
  for (int m = 0; m < 4; m++) {
#pragma unroll
    for (int n = 0; n < 2; n++) {
      int col = w * 32 + n * 16 + lc;
      float p[8];
#pragma unroll
      for (int k = 0; k < 8; k++)
        p[k] = fmaxf(h3l[(m * 16 + 2 * k) * 132 + col],
                     h3l[(m * 16 + 2 * k + 1) * 132 + col]);
      float bb = n ? b1 : b0;
#pragma unroll
      for (int r = 0; r < 4; r++) {
        float y1 = 0.f;
#pragma unroll
        for (int k = 0; k < 8; k++) y1 += fc[r][k] * p[k];
        int grow = row0 + m * 16 + lg * 4 + r;
        out[grow * 256 + g0 + col] = accO[m][n][r] + 0.5f * y1 + bb;
      }
    }
  }
}

// ============================ launcher ============================
extern "C" void kernel_launch(void* const* d_in, const int* in_sizes, int n_in,
                              void* d_out, int out_size, void* d_ws, size_t ws_size,
                              hipStream_t stream) {
  const float* x    = (const float*)d_in[0];
  const float* W    = (const float*)d_in[1];
  const float* MM   = (const float*)d_in[2];
  const float* e    = (const float*)d_in[3];
  const float* bias = (const float*)d_in[4];
  const int* rows   = (const int*)d_in[5];
  const int* cols   = (const int*)d_in[6];
  float* out = (float*)d_out;
  char* ws = (char*)d_ws;

  prep_kernel<<<193, 256, 0, stream>>>(W, MM, e, rows, cols, ws);
  glgc_main<<<4096, 256, 0, stream>>>(x, bias, ws, out);
}